// Round 1
// baseline (140.119 us; speedup 1.0000x reference)
//
#include <hip/hip_runtime.h>
#include <hip/hip_bf16.h>
#include <math.h>

// Problem: x[N=16,T=128,V=64,F=16] fp32, a[F=16] fp32.
// score[n,i,j] = (1/T) * sum_t sum_f a[f]*|x[n,t,i,f]-x[n,t,j,f]|
// e = exp(relu(score)); out[n,i,j] = e[n,i,j] / sum_i e[n,i,j]   (column norm)

#define Nn 16
#define Tt 128
#define Vv 64
#define Ff 16
#define CHUNKS 16      // T split into 16 chunks of 8
#define TC 8
#define PITCH 20       // LDS row pitch in floats: 16B-aligned (80B), bank-spread

// ---------------- Kernel 1: partial weighted-L1 scores per t-chunk ----------
// grid = (CHUNKS, Nn), block = 512. ws layout: [c][n][j][i] fp32.
__global__ __launch_bounds__(512, 2) void gls_scores(const float* __restrict__ x,
                                                     const float* __restrict__ a,
                                                     float* __restrict__ ws) {
    __shared__ float xs[TC * Vv * PITCH];   // 8*64*20*4 = 40 KB

    const int c   = blockIdx.x;
    const int n   = blockIdx.y;
    const int tid = threadIdx.x;

    // ---- stage x[n, c*8 .. c*8+7, :, :]  (8192 floats = 2048 float4) ----
    const float4* xg = (const float4*)(x + (size_t)(n * Tt + c * TC) * (Vv * Ff));
#pragma unroll
    for (int k = 0; k < 4; ++k) {
        const int f4  = tid + k * 512;
        const float4 val = xg[f4];
        const int p   = f4 << 2;       // float index within slice
        const int tl  = p >> 10;       // /(V*F)
        const int rem = p & 1023;
        const int v   = rem >> 4;      // /F
        const int f   = rem & 15;      // multiple of 4
        *(float4*)&xs[(tl * Vv + v) * PITCH + f] = val;
    }

    float af[16];
#pragma unroll
    for (int f = 0; f < 16; ++f) af[f] = a[f];   // uniform -> scalarized

    __syncthreads();

    const int i  = tid & 63;          // lane == vertex i (per wave)
    const int j0 = (tid >> 6) * 8;    // 8 waves x 8 j's = 64 j's

    float acc[8] = {0.f, 0.f, 0.f, 0.f, 0.f, 0.f, 0.f, 0.f};

    for (int tt = 0; tt < TC; ++tt) {
        const float* xi = &xs[(tt * Vv + i) * PITCH];
        const float4 A0 = *(const float4*)(xi);
        const float4 A1 = *(const float4*)(xi + 4);
        const float4 A2 = *(const float4*)(xi + 8);
        const float4 A3 = *(const float4*)(xi + 12);
#pragma unroll
        for (int jj = 0; jj < 8; ++jj) {
            // wave-uniform address -> LDS broadcast read
            const float* xj = &xs[(tt * Vv + j0 + jj) * PITCH];
            const float4 B0 = *(const float4*)(xj);
            const float4 B1 = *(const float4*)(xj + 4);
            const float4 B2 = *(const float4*)(xj + 8);
            const float4 B3 = *(const float4*)(xj + 12);
            float s = acc[jj];
            s = fmaf(fabsf(A0.x - B0.x), af[0],  s);
            s = fmaf(fabsf(A0.y - B0.y), af[1],  s);
            s = fmaf(fabsf(A0.z - B0.z), af[2],  s);
            s = fmaf(fabsf(A0.w - B0.w), af[3],  s);
            s = fmaf(fabsf(A1.x - B1.x), af[4],  s);
            s = fmaf(fabsf(A1.y - B1.y), af[5],  s);
            s = fmaf(fabsf(A1.z - B1.z), af[6],  s);
            s = fmaf(fabsf(A1.w - B1.w), af[7],  s);
            s = fmaf(fabsf(A2.x - B2.x), af[8],  s);
            s = fmaf(fabsf(A2.y - B2.y), af[9],  s);
            s = fmaf(fabsf(A2.z - B2.z), af[10], s);
            s = fmaf(fabsf(A2.w - B2.w), af[11], s);
            s = fmaf(fabsf(A3.x - B3.x), af[12], s);
            s = fmaf(fabsf(A3.y - B3.y), af[13], s);
            s = fmaf(fabsf(A3.z - B3.z), af[14], s);
            s = fmaf(fabsf(A3.w - B3.w), af[15], s);
            acc[jj] = s;
        }
    }

    // ws[c][n][j][i] — lane-i contiguous => coalesced scalar stores
    float* wsc = ws + (size_t)(c * Nn + n) * (Vv * Vv);
#pragma unroll
    for (int jj = 0; jj < 8; ++jj)
        wsc[(j0 + jj) * Vv + i] = acc[jj];
}

// ---------------- Kernel 2: chunk-reduce + exp(relu) + column-normalize -----
// grid = Nn, block = 256.
#define OPITCH 68   // 64 + 4: 16B-aligned rows, bank-spread for scatter
__global__ __launch_bounds__(256) void gls_norm(const float* __restrict__ ws,
                                                float* __restrict__ out) {
    __shared__ float es[Vv * OPITCH];   // ~17.4 KB

    const int n   = blockIdx.x;
    const int tid = threadIdx.x;
    const int i   = tid & 63;     // lane == row index i (the reduction axis)
    const int j2  = tid >> 6;     // wave id -> 16 columns per wave

#pragma unroll
    for (int jj = 0; jj < 16; ++jj) {
        const int j = j2 * 16 + jj;       // wave-uniform column
        float s = 0.f;
#pragma unroll
        for (int cc = 0; cc < CHUNKS; ++cc)
            s += ws[((size_t)(cc * Nn + n) * Vv + j) * Vv + i];  // lane-coalesced
        const float e = expf(fmaxf(s * (1.0f / (float)Tt), 0.0f));
        // column sum over i == butterfly over the 64 lanes
        float tsum = e;
#pragma unroll
        for (int m = 1; m < 64; m <<= 1) tsum += __shfl_xor(tsum, m, 64);
        es[i * OPITCH + j] = e / tsum;
    }

    __syncthreads();

    // coalesced float4 stores of out[n][i][j]
    const int ii = tid >> 2;
    const int q  = tid & 3;
    float* on = out + (size_t)n * (Vv * Vv);
#pragma unroll
    for (int k = 0; k < 4; ++k) {
        const int col = q * 16 + k * 4;
        *(float4*)&on[ii * Vv + col] = *(const float4*)&es[ii * OPITCH + col];
    }
}

extern "C" void kernel_launch(void* const* d_in, const int* in_sizes, int n_in,
                              void* d_out, int out_size, void* d_ws, size_t ws_size,
                              hipStream_t stream) {
    const float* x = (const float*)d_in[0];   // [16,128,64,16]
    const float* a = (const float*)d_in[1];   // [16,1]
    float* out = (float*)d_out;               // [16,64,64]
    float* ws  = (float*)d_ws;                // needs 16*16*64*64*4 = 4 MB

    dim3 g1(CHUNKS, Nn);
    gls_scores<<<g1, 512, 0, stream>>>(x, a, ws);
    gls_norm<<<Nn, 256, 0, stream>>>(ws, out);
}

// Round 2
// 70.286 us; speedup vs baseline: 1.9935x; 1.9935x over previous
//
#include <hip/hip_runtime.h>
#include <hip/hip_bf16.h>
#include <math.h>

// Problem: x[N=16,T=128,V=64,F=16] fp32, a[F=16] fp32.
// score[n,i,j] = (1/T) * sum_t sum_f a[f]*|x[n,t,i,f]-x[n,t,j,f]|
// e = exp(relu(score)); out[n,i,j] = e[n,i,j] / sum_i e[n,i,j]   (column norm)

#define Nn 16
#define Tt 128
#define Vv 64
#define Ff 16
#define CHUNKS 16   // T split into 16 chunks of 8
#define TC 8
#define JSPLIT 4    // j split into 4 groups of 16 per block
#define JPW 4       // j's per wave (4 waves x 4 j = 16 j per block)

// ---------------- Kernel 1: partial weighted-L1 scores per t-chunk ----------
// grid = (CHUNKS, Nn, JSPLIT), block = 256 (4 waves). No LDS, no barriers.
// A-operand: lane-coalesced float4 global loads (lane = vertex i).
// B-operand: wave-uniform global loads (scalar path / L1 broadcast).
// ws layout: [n][c][j][i] fp32  (4 MB total).
__global__ __launch_bounds__(256) void gls_scores(const float* __restrict__ x,
                                                  const float* __restrict__ a,
                                                  float* __restrict__ ws) {
    const int c   = blockIdx.x;
    const int n   = blockIdx.y;
    const int z   = blockIdx.z;
    const int tid = threadIdx.x;
    const int i   = tid & 63;
    // force wave id into an SGPR so B addresses are provably wave-uniform
    const int w   = __builtin_amdgcn_readfirstlane(tid >> 6);
    const int j0  = z * (Vv / JSPLIT) + w * JPW;

    // a[f]: uniform -> scalar regs
    float af[Ff];
#pragma unroll
    for (int f = 0; f < Ff; ++f) af[f] = a[f];

    float acc[JPW] = {0.f, 0.f, 0.f, 0.f};

    const float* xnc = x + (size_t)(n * Tt + c * TC) * (Vv * Ff);

#pragma unroll 2
    for (int tt = 0; tt < TC; ++tt) {
        const float* xt = xnc + tt * (Vv * Ff);
        // A: lane i's 16 features (64B contiguous per lane -> coalesced)
        const float4 A0 = *(const float4*)(xt + i * Ff + 0);
        const float4 A1 = *(const float4*)(xt + i * Ff + 4);
        const float4 A2 = *(const float4*)(xt + i * Ff + 8);
        const float4 A3 = *(const float4*)(xt + i * Ff + 12);
#pragma unroll
        for (int jj = 0; jj < JPW; ++jj) {
            const float* xb = xt + (j0 + jj) * Ff;   // wave-uniform address
            const float4 B0 = *(const float4*)(xb + 0);
            const float4 B1 = *(const float4*)(xb + 4);
            const float4 B2 = *(const float4*)(xb + 8);
            const float4 B3 = *(const float4*)(xb + 12);
            float s = acc[jj];
            s = fmaf(fabsf(A0.x - B0.x), af[0],  s);
            s = fmaf(fabsf(A0.y - B0.y), af[1],  s);
            s = fmaf(fabsf(A0.z - B0.z), af[2],  s);
            s = fmaf(fabsf(A0.w - B0.w), af[3],  s);
            s = fmaf(fabsf(A1.x - B1.x), af[4],  s);
            s = fmaf(fabsf(A1.y - B1.y), af[5],  s);
            s = fmaf(fabsf(A1.z - B1.z), af[6],  s);
            s = fmaf(fabsf(A1.w - B1.w), af[7],  s);
            s = fmaf(fabsf(A2.x - B2.x), af[8],  s);
            s = fmaf(fabsf(A2.y - B2.y), af[9],  s);
            s = fmaf(fabsf(A2.z - B2.z), af[10], s);
            s = fmaf(fabsf(A2.w - B2.w), af[11], s);
            s = fmaf(fabsf(A3.x - B3.x), af[12], s);
            s = fmaf(fabsf(A3.y - B3.y), af[13], s);
            s = fmaf(fabsf(A3.z - B3.z), af[14], s);
            s = fmaf(fabsf(A3.w - B3.w), af[15], s);
            acc[jj] = s;
        }
    }

    // ws[n][c][j][i] — lane-i contiguous => coalesced 256B stores
    float* wsb = ws + (((size_t)n * CHUNKS + c) * Vv + j0) * Vv;
#pragma unroll
    for (int jj = 0; jj < JPW; ++jj)
        wsb[jj * Vv + i] = acc[jj];
}

// ---------------- Kernel 2: chunk-reduce + exp(relu) + column-normalize -----
// grid = (Nn, 16), block = 256 (4 waves). One (n,j) column per wave.
__global__ __launch_bounds__(256) void gls_norm(const float* __restrict__ ws,
                                                float* __restrict__ out) {
    const int n   = blockIdx.x;
    const int jq  = blockIdx.y;          // 0..15
    const int tid = threadIdx.x;
    const int i   = tid & 63;            // lane == row index i (reduction axis)
    const int w   = tid >> 6;
    const int j   = jq * 4 + w;          // this wave's column

    const float* wsn = ws + (size_t)n * CHUNKS * (Vv * Vv);
    float s = 0.f;
#pragma unroll
    for (int cc = 0; cc < CHUNKS; ++cc)
        s += wsn[(cc * Vv + j) * Vv + i];     // lane-coalesced 256B loads

    const float e = expf(fmaxf(s * (1.0f / (float)Tt), 0.0f));
    float tsum = e;
#pragma unroll
    for (int m = 1; m < 64; m <<= 1) tsum += __shfl_xor(tsum, m, 64);

    // scatter store (stride 256B per lane) — tiny total, L2 write-combines
    out[((size_t)n * Vv + i) * Vv + j] = e / tsum;
}

extern "C" void kernel_launch(void* const* d_in, const int* in_sizes, int n_in,
                              void* d_out, int out_size, void* d_ws, size_t ws_size,
                              hipStream_t stream) {
    const float* x = (const float*)d_in[0];   // [16,128,64,16]
    const float* a = (const float*)d_in[1];   // [16,1]
    float* out = (float*)d_out;               // [16,64,64]
    float* ws  = (float*)d_ws;                // 16*16*64*64*4 = 4 MB

    dim3 g1(CHUNKS, Nn, JSPLIT);
    gls_scores<<<g1, 256, 0, stream>>>(x, a, ws);
    dim3 g2(Nn, 16);
    gls_norm<<<g2, 256, 0, stream>>>(ws, out);
}

// Round 3
// 70.036 us; speedup vs baseline: 2.0007x; 1.0036x over previous
//
#include <hip/hip_runtime.h>
#include <hip/hip_bf16.h>
#include <math.h>

// Problem: x[N=16,T=128,V=64,F=16] fp32, a[F=16] fp32.
// score[n,i,j] = (1/T) * sum_t sum_f a[f]*|x[n,t,i,f]-x[n,t,j,f]|
// e = exp(relu(score)); out[n,i,j] = e[n,i,j] / sum_i e[n,i,j]   (column norm)

#define Nn 16
#define Tt 128
#define Vv 64
#define Ff 16
#define CHUNKS 32   // T split into 32 chunks of 4
#define TC 4
#define JSPLIT 4    // j split into 4 groups of 16 per block
#define JPW 4       // j's per wave (4 waves x 4 j = 16 j per block)
#define PITCH 20    // LDS row pitch (floats): 80 B => 16B-group stride 5 mod 8
                    // -> uniform spread over all 8 LDS superbanks for b128

// ---------------- Kernel 1: partial weighted-L1 scores per t-chunk ----------
// grid = (CHUNKS, Nn, JSPLIT), block = 256 (4 waves), LDS 20 KB -> 8 blocks/CU.
// Staging: ONE coalesced dwordx4 per thread per k (lane-contiguous).
// A: lane-strided b128 from LDS (conflict-optimal pitch). B: uniform LDS bcast.
// ws layout: [n][c][j][i] fp32  (8 MB total).
__global__ __launch_bounds__(256, 8) void gls_scores(const float* __restrict__ x,
                                                     const float* __restrict__ a,
                                                     float* __restrict__ ws) {
    __shared__ float xs[TC * Vv * PITCH];   // 4*64*20*4 = 20 KB

    const int c   = blockIdx.x;
    const int n   = blockIdx.y;
    const int z   = blockIdx.z;
    const int tid = threadIdx.x;
    const int i   = tid & 63;
    const int w   = __builtin_amdgcn_readfirstlane(tid >> 6);
    const int j0  = z * (Vv / JSPLIT) + w * JPW;

    // ---- stage x[n, c*4 .. c*4+3, :, :]  (4096 floats = 1024 float4) ----
    const float4* xg = (const float4*)(x + (size_t)(n * Tt + c * TC) * (Vv * Ff));
#pragma unroll
    for (int k = 0; k < 4; ++k) {
        const int f4  = tid + k * 256;      // coalesced: lane-contiguous float4
        const float4 val = xg[f4];
        const int p   = f4 << 2;
        const int tl  = p >> 10;            // /(V*F)
        const int rem = p & 1023;
        const int v   = rem >> 4;           // /F
        const int f   = rem & 15;
        *(float4*)&xs[(tl * Vv + v) * PITCH + f] = val;
    }

    float af[Ff];
#pragma unroll
    for (int f = 0; f < Ff; ++f) af[f] = a[f];   // uniform -> SGPRs

    __syncthreads();

    float acc[JPW] = {0.f, 0.f, 0.f, 0.f};

#pragma unroll
    for (int tt = 0; tt < TC; ++tt) {
        const float* xi = &xs[(tt * Vv + i) * PITCH];
        const float4 A0 = *(const float4*)(xi);
        const float4 A1 = *(const float4*)(xi + 4);
        const float4 A2 = *(const float4*)(xi + 8);
        const float4 A3 = *(const float4*)(xi + 12);
#pragma unroll
        for (int jj = 0; jj < JPW; ++jj) {
            const float* xj = &xs[(tt * Vv + j0 + jj) * PITCH]; // uniform -> bcast
            const float4 B0 = *(const float4*)(xj);
            const float4 B1 = *(const float4*)(xj + 4);
            const float4 B2 = *(const float4*)(xj + 8);
            const float4 B3 = *(const float4*)(xj + 12);
            float s = acc[jj];
            s = fmaf(fabsf(A0.x - B0.x), af[0],  s);
            s = fmaf(fabsf(A0.y - B0.y), af[1],  s);
            s = fmaf(fabsf(A0.z - B0.z), af[2],  s);
            s = fmaf(fabsf(A0.w - B0.w), af[3],  s);
            s = fmaf(fabsf(A1.x - B1.x), af[4],  s);
            s = fmaf(fabsf(A1.y - B1.y), af[5],  s);
            s = fmaf(fabsf(A1.z - B1.z), af[6],  s);
            s = fmaf(fabsf(A1.w - B1.w), af[7],  s);
            s = fmaf(fabsf(A2.x - B2.x), af[8],  s);
            s = fmaf(fabsf(A2.y - B2.y), af[9],  s);
            s = fmaf(fabsf(A2.z - B2.z), af[10], s);
            s = fmaf(fabsf(A2.w - B2.w), af[11], s);
            s = fmaf(fabsf(A3.x - B3.x), af[12], s);
            s = fmaf(fabsf(A3.y - B3.y), af[13], s);
            s = fmaf(fabsf(A3.z - B3.z), af[14], s);
            s = fmaf(fabsf(A3.w - B3.w), af[15], s);
            acc[jj] = s;
        }
    }

    // ws[n][c][j][i] — lane-i contiguous => coalesced 256B stores
    float* wsb = ws + (((size_t)n * CHUNKS + c) * Vv + j0) * Vv;
#pragma unroll
    for (int jj = 0; jj < JPW; ++jj)
        wsb[jj * Vv + i] = acc[jj];
}

// ---------------- Kernel 2: chunk-reduce + exp(relu) + column-normalize -----
// grid = (Nn, 16), block = 256 (4 waves). One (n,j) column per wave.
__global__ __launch_bounds__(256) void gls_norm(const float* __restrict__ ws,
                                                float* __restrict__ out) {
    const int n   = blockIdx.x;
    const int jq  = blockIdx.y;          // 0..15
    const int tid = threadIdx.x;
    const int i   = tid & 63;            // lane == row index i (reduction axis)
    const int w   = tid >> 6;
    const int j   = jq * 4 + w;          // this wave's column

    const float* wsn = ws + (size_t)n * CHUNKS * (Vv * Vv);
    float s = 0.f;
#pragma unroll
    for (int cc = 0; cc < CHUNKS; ++cc)
        s += wsn[(cc * Vv + j) * Vv + i];     // lane-coalesced 256B loads

    const float e = expf(fmaxf(s * (1.0f / (float)Tt), 0.0f));
    float tsum = e;
#pragma unroll
    for (int m = 1; m < 64; m <<= 1) tsum += __shfl_xor(tsum, m, 64);

    // scatter store (stride 256B per lane) — tiny total (256 KB chip-wide)
    out[((size_t)n * Vv + i) * Vv + j] = e / tsum;
}

extern "C" void kernel_launch(void* const* d_in, const int* in_sizes, int n_in,
                              void* d_out, int out_size, void* d_ws, size_t ws_size,
                              hipStream_t stream) {
    const float* x = (const float*)d_in[0];   // [16,128,64,16]
    const float* a = (const float*)d_in[1];   // [16,1]
    float* out = (float*)d_out;               // [16,64,64]
    float* ws  = (float*)d_ws;                // 16*32*64*64*4 = 8 MB

    dim3 g1(CHUNKS, Nn, JSPLIT);
    gls_scores<<<g1, 256, 0, stream>>>(x, a, ws);
    dim3 g2(Nn, 16);
    gls_norm<<<g2, 256, 0, stream>>>(ws, out);
}